// Round 5
// baseline (289.057 us; speedup 1.0000x reference)
//
#include <hip/hip_runtime.h>
#include <stdint.h>

typedef __attribute__((ext_vector_type(8))) short short8;
typedef __attribute__((ext_vector_type(4))) float float4v;

#define HW   4096
#define CC   256
#define SEQQ 32
#define BSZ  32
#define RPB  256   // rows per block (4 waves x 64 rows, 4 chunks of 16 each)

// Tiled ctx layout (per batch): [s>>2][c>>4][s&3][c&15] shorts.
// s-group = 16 c-tiles x 64 = 1024 shorts, padded to 1032 (bank de-phase).
#define SGRP     1032
#define CTXT_SZ  (8 * SGRP)          // 8256 shorts per batch
#define PSTR_P   40                  // pL row stride (shorts)

static __device__ __forceinline__ uint16_t f2bf(float f) {
  union { float f; uint32_t u; } v; v.f = f;
  uint32_t r = v.u + 0x7FFFu + ((v.u >> 16) & 1u);
  return (uint16_t)(r >> 16);
}
static __device__ __forceinline__ float bf2f(uint16_t h) {
  union { uint32_t u; float f; } v; v.u = ((uint32_t)h) << 16;
  return v.f;
}

// ---------------------------------------------------------------------------
// Prep: ctx = context @ W (fp32 accum), split to bf16 hi/lo in TILED layout,
// plus mask -> 32-word bitmask (with storage-format autodetection).
// ---------------------------------------------------------------------------
extern "C" __global__ __launch_bounds__(256) void prep_kernel(
    const float* __restrict__ ctx_in,   // [32][32][256]
    const float* __restrict__ Wp,       // [256][256]
    const void*  __restrict__ mask,     // [32][32] unknown storage
    uint32_t* __restrict__ maskbits_ws, // [32] bitmask words
    uint16_t* __restrict__ hiT_ws,      // [32][8256] tiled bf16 hi
    uint16_t* __restrict__ loT_ws)      // [32][8256] tiled bf16 lo
{
  const int t = threadIdx.x;
  if (blockIdx.x == 256) {
    __shared__ int byteFlag;
    if (t == 0) byteFlag = 0;
    __syncthreads();
    const uint8_t* mb = (const uint8_t*)mask;
    int nz = 0;
    for (int i = t; i < 1024; i += 256)
      if ((i & 3) == 1 && mb[i] != 0) nz = 1;
    if (nz) atomicOr(&byteFlag, 1);
    __syncthreads();
    const bool byteMode = (byteFlag != 0);
    const uint32_t* mw32 = (const uint32_t*)mask;
    if (t < 32) {
      uint32_t bits = 0;
      for (int s = 0; s < 32; ++s) {
        bool m = byteMode ? (mb[t * 32 + s] != 0) : (mw32[t * 32 + s] != 0);
        if (m) bits |= (1u << s);
      }
      maskbits_ws[t] = bits;
    }
    return;
  }

  const int r0 = blockIdx.x * 4;
  __shared__ float crow[4][CC];
  for (int i = t; i < 1024; i += 256)
    crow[i >> 8][i & 255] = ctx_in[(size_t)r0 * CC + i];
  __syncthreads();

  const int j  = t >> 6;
  const int c4 = (t & 63) << 2;
  float4v acc = {0.f, 0.f, 0.f, 0.f};
  #pragma unroll 8
  for (int d = 0; d < CC; ++d) {
    float s = crow[j][d];
    const float4 wv = *(const float4*)&Wp[(size_t)d * CC + c4];
    acc[0] += s * wv.x; acc[1] += s * wv.y;
    acc[2] += s * wv.z; acc[3] += s * wv.w;
  }

  const int row = r0 + j, bb = row >> 5, ss = row & 31;
  const size_t base = (size_t)bb * CTXT_SZ + (ss >> 2) * SGRP + (ss & 3) * 16;
  #pragma unroll
  for (int q = 0; q < 4; ++q) {
    const int c = c4 + q;
    const float v = acc[q];
    const uint16_t h  = f2bf(v);
    const uint16_t lo = f2bf(v - bf2f(h));
    const size_t idx = base + (c >> 4) * 64 + (c & 15);
    hiT_ws[idx] = h;
    loT_ws[idx] = lo;
  }
}

// Issue all 16 x dwordx4 loads for one 16-row chunk into named reg buffers.
#define LOAD_CHUNK(XA, XB, CIDX)                                              \
  {                                                                           \
    const float* xr_ = xrow0 + (CIDX) * 16 * CC;                              \
    _Pragma("unroll")                                                         \
    for (int k0 = 0; k0 < 8; ++k0) {                                          \
      XA[k0] = *(const float4*)(xr_ + k0 * 32);                               \
      XB[k0] = *(const float4*)(xr_ + k0 * 32 + 4);                           \
    }                                                                         \
  }                                                                           \
  asm volatile("" ::: "memory");  /* pin: loads may not sink below */

// One 16-row chunk: phase1 split-bf16 MFMA (swapped operands), lane-owns-row
// softmax, then per-wave XOR-swizzled LDS transpose epilogues so every global
// store is full-128B-line, issued as NON-TEMPORAL (written once, never
// re-read in-kernel -> no L2 dirty churn against the read stream).
#define COMPUTE_TILE(XA, XB, TBASE)                                           \
  {                                                                           \
    float4v acc0 = {0.f, 0.f, 0.f, 0.f};                                      \
    float4v acc1 = {0.f, 0.f, 0.f, 0.f};                                      \
    _Pragma("unroll")                                                         \
    for (int k0 = 0; k0 < 8; ++k0) {                                          \
      float xv[8] = {XA[k0].x, XA[k0].y, XA[k0].z, XA[k0].w,                  \
                     XB[k0].x, XB[k0].y, XB[k0].z, XB[k0].w};                 \
      short8 ah, al;                                                          \
      _Pragma("unroll")                                                       \
      for (int jj = 0; jj < 8; ++jj) {                                        \
        uint32_t u = __float_as_uint(xv[jj]);                                 \
        ah[jj] = (short)(u >> 16);                                            \
        float rr_ = xv[jj] - __uint_as_float(u & 0xFFFF0000u);                \
        al[jj] = (short)(__float_as_uint(rr_) >> 16);                         \
      }                                                                       \
      const int ka = sbase + k0 * 128;                                        \
      short8 bh0 = *(const short8*)&hiT[ka];                                  \
      short8 bl0 = *(const short8*)&loT[ka];                                  \
      short8 bh1 = *(const short8*)&hiT[ka + 4 * SGRP];                       \
      short8 bl1 = *(const short8*)&loT[ka + 4 * SGRP];                       \
      acc0 = __builtin_amdgcn_mfma_f32_16x16x32_bf16(bh0, ah, acc0, 0, 0, 0); \
      acc0 = __builtin_amdgcn_mfma_f32_16x16x32_bf16(bl0, ah, acc0, 0, 0, 0); \
      acc0 = __builtin_amdgcn_mfma_f32_16x16x32_bf16(bh0, al, acc0, 0, 0, 0); \
      acc1 = __builtin_amdgcn_mfma_f32_16x16x32_bf16(bh1, ah, acc1, 0, 0, 0); \
      acc1 = __builtin_amdgcn_mfma_f32_16x16x32_bf16(bl1, ah, acc1, 0, 0, 0); \
      acc1 = __builtin_amdgcn_mfma_f32_16x16x32_bf16(bh1, al, acc1, 0, 0, 0); \
    }                                                                         \
    const int n = (TBASE) + l15;                                              \
    const uint32_t mwd = maskW[n & 31];                                       \
    float v[8];                                                               \
    _Pragma("unroll")                                                         \
    for (int r = 0; r < 4; ++r) {                                             \
      v[r]     = (mwd & (1u << (quad * 4 + r)))      ? -1e30f : acc0[r];      \
      v[4 + r] = (mwd & (1u << (16 + quad * 4 + r))) ? -1e30f : acc1[r];      \
    }                                                                         \
    float mx = v[0];                                                          \
    _Pragma("unroll")                                                         \
    for (int jq = 1; jq < 8; ++jq) mx = fmaxf(mx, v[jq]);                     \
    mx = fmaxf(mx, __shfl_xor(mx, 16, 64));                                   \
    mx = fmaxf(mx, __shfl_xor(mx, 32, 64));                                   \
    float e[8], sm = 0.f;                                                     \
    _Pragma("unroll")                                                         \
    for (int jq = 0; jq < 8; ++jq) { e[jq] = __expf(v[jq] - mx); sm += e[jq]; } \
    sm += __shfl_xor(sm, 16, 64);                                             \
    sm += __shfl_xor(sm, 32, 64);                                             \
    const float inv = 1.0f / sm;                                              \
    float p[8];                                                               \
    _Pragma("unroll")                                                         \
    for (int jq = 0; jq < 8; ++jq) p[jq] = e[jq] * inv;                       \
    /* out1 via XOR-swizzled LDS transpose ([16][32] f32, 8 slots/row) */     \
    const int r8 = l15 & 7;                                                   \
    float4v p03 = {p[0], p[1], p[2], p[3]};                                   \
    float4v p47 = {p[4], p[5], p[6], p[7]};                                   \
    *(float4v*)&ostW[l15 * 32 + ((quad ^ r8) << 2)]       = p03;              \
    *(float4v*)&ostW[l15 * 32 + (((4 + quad) ^ r8) << 2)] = p47;              \
    uint32_t w0 = (uint32_t)f2bf(p[0]) | ((uint32_t)f2bf(p[1]) << 16);        \
    uint32_t w1 = (uint32_t)f2bf(p[2]) | ((uint32_t)f2bf(p[3]) << 16);        \
    uint32_t w2 = (uint32_t)f2bf(p[4]) | ((uint32_t)f2bf(p[5]) << 16);        \
    uint32_t w3 = (uint32_t)f2bf(p[6]) | ((uint32_t)f2bf(p[7]) << 16);        \
    uint16_t* prow = &pL[(w * 16 + l15) * PSTR_P];                            \
    *(uint2*)(prow + quad * 4)      = make_uint2(w0, w1);                     \
    *(uint2*)(prow + 16 + quad * 4) = make_uint2(w2, w3);                     \
    _Pragma("unroll")                                                         \
    for (int i2 = 0; i2 < 2; ++i2) {                                          \
      const int rr = 8 * i2 + (lane >> 3);                                    \
      const int mm = lane & 7;                                                \
      float4v vv = *(const float4v*)&ostW[rr * 32 + ((mm ^ (rr & 7)) << 2)];  \
      __builtin_nontemporal_store(vv,                                         \
        (float4v*)(out1 + ((size_t)b * HW + (TBASE) + rr) * SEQQ + mm * 4));  \
    }                                                                         \
    /* phase 2: per 64-ch group, MFMA -> LDS transpose -> full-line stores */ \
    short8 pa = *(const short8*)&pL[(w * 16 + l15) * PSTR_P + quad * 8];      \
    _Pragma("unroll")                                                         \
    for (int cg = 0; cg < 4; ++cg) {                                          \
      _Pragma("unroll")                                                       \
      for (int j2 = 0; j2 < 4; ++j2) {                                        \
        const int ct = cg * 4 + j2;                                           \
        short8 bfr;                                                           \
        _Pragma("unroll")                                                     \
        for (int jj = 0; jj < 8; ++jj)                                        \
          bfr[jj] = (short)hiT[cbase + (jj >> 2) * SGRP + ct * 64 + (jj & 3) * 16]; \
        float4v z = {0.f, 0.f, 0.f, 0.f};                                     \
        float4v dd = __builtin_amdgcn_mfma_f32_16x16x32_bf16(bfr, pa, z, 0, 0, 0); \
        const int ss = j2 * 4 + quad;                                         \
        *(float4v*)&ostW[l15 * 64 + ((ss ^ l15) << 2)] = dd;                  \
      }                                                                       \
      _Pragma("unroll")                                                       \
      for (int i2 = 0; i2 < 4; ++i2) {                                        \
        const int rr = 4 * i2 + (lane >> 4);                                  \
        const int mm = lane & 15;                                             \
        float4v vv = *(const float4v*)&ostW[rr * 64 + ((mm ^ rr) << 2)];      \
        __builtin_nontemporal_store(vv,                                       \
          (float4v*)(out0 + ((size_t)b * HW + (TBASE) + rr) * CC + cg * 64 + mm * 4)); \
      }                                                                       \
    }                                                                         \
  }

// ---------------------------------------------------------------------------
// Main fused kernel. Round-5 change: persistent waves, barrier-free steady
// state. Wave owns 64 rows = 4 chunks; rolling depth-2 pipeline with named
// A/B reg buffers keeps ~16 loads in flight WHILE previous chunk's stores
// drain. 8 unsynchronized waves/CU in different phases -> continuous mixed
// R/W traffic instead of burst->drain cycles. Stores are non-temporal.
// ---------------------------------------------------------------------------
extern "C" __global__ __launch_bounds__(256, 2) void attn_main(
    const float* __restrict__ x,        // [32][4096][256]
    const uint8_t* __restrict__ ws,
    float* __restrict__ out0,           // weighted_context [32][4096][256]
    float* __restrict__ out1)           // word_attn        [32][4096][32]
{
  const uint32_t* maskbits_ws = (const uint32_t*)ws;
  const uint16_t* hiT_ws = (const uint16_t*)(ws + 128);
  const uint16_t* loT_ws = hiT_ws + (size_t)BSZ * CTXT_SZ;

  __shared__ __align__(16) uint16_t hiT[CTXT_SZ];      // 16512 B
  __shared__ __align__(16) uint16_t loT[CTXT_SZ];      // 16512 B
  __shared__ __align__(16) uint16_t pL[64 * PSTR_P];   // 5120 B
  __shared__ __align__(16) float    oStgF[4 * 1024];   // 16384 B (4KB/wave)
  __shared__ uint32_t maskW[32];

  const int tid = threadIdx.x;
  const int b   = blockIdx.y;
  const int n0  = blockIdx.x * RPB;

  const int w    = tid >> 6;
  const int lane = tid & 63;
  const int l15  = lane & 15;
  const int quad = lane >> 4;
  const int nwave = n0 + w * 64;     // wave owns 64 rows (4 chunks of 16)
  float* ostW = &oStgF[w * 1024];

  const uint4* sHi = (const uint4*)(hiT_ws + (size_t)b * CTXT_SZ);
  const uint4* sLo = (const uint4*)(loT_ws + (size_t)b * CTXT_SZ);

  // ---- issue staging loads (regs) ----
  uint4 hS[4], lS[4];
  #pragma unroll
  for (int k = 0; k < 4; ++k) {
    hS[k] = sHi[tid + k * 256];
    lS[k] = sLo[tid + k * 256];
  }

  // ---- issue chunk-0 x loads (in flight across the staging barrier) ----
  const float* xrow0 = x + ((size_t)b * HW + nwave + l15) * CC + quad * 8;
  float4 xa0[8], xb0[8], xa1[8], xb1[8];
  LOAD_CHUNK(xa0, xb0, 0);

  // ---- LDS writes + the ONLY barrier ----
  {
    uint4* dHi = (uint4*)hiT;
    uint4* dLo = (uint4*)loT;
    #pragma unroll
    for (int k = 0; k < 4; ++k) {
      dHi[tid + k * 256] = hS[k];
      dLo[tid + k * 256] = lS[k];
    }
    if (tid < 8) { dHi[1024 + tid] = sHi[1024 + tid]; dLo[1024 + tid] = sLo[1024 + tid]; }
    if (tid < 32) maskW[tid] = maskbits_ws[tid];
  }
  __syncthreads();

  const int sbase = (l15 >> 2) * SGRP + (l15 & 3) * 16 + (quad >> 1) * 64 + (quad & 1) * 8;
  const int cbase = quad * 2 * SGRP + l15;

  // ---- barrier-free rolling pipeline over 4 chunks ----
  LOAD_CHUNK(xa1, xb1, 1);
  COMPUTE_TILE(xa0, xb0, nwave);
  LOAD_CHUNK(xa0, xb0, 2);
  COMPUTE_TILE(xa1, xb1, nwave + 16);
  LOAD_CHUNK(xa1, xb1, 3);
  COMPUTE_TILE(xa0, xb0, nwave + 32);
  COMPUTE_TILE(xa1, xb1, nwave + 48);
}

// ---------------------------------------------------------------------------
extern "C" void kernel_launch(void* const* d_in, const int* in_sizes, int n_in,
                              void* d_out, int out_size, void* d_ws, size_t ws_size,
                              hipStream_t stream) {
  const float* x      = (const float*)d_in[0];
  // d_in[1] = sentence (unused by reference call())
  const float* ctx_in = (const float*)d_in[2];
  const void*  mask   = d_in[3];
  const float* Wp     = (const float*)d_in[4];

  float* out0 = (float*)d_out;                       // [32][4096][256]
  float* out1 = out0 + (size_t)BSZ * HW * CC;        // [32][4096][32]

  uint8_t*  ws          = (uint8_t*)d_ws;
  uint32_t* maskbits_ws = (uint32_t*)ws;                         // 128 B
  uint16_t* hiT_ws      = (uint16_t*)(ws + 128);                 // 528384 B
  uint16_t* loT_ws      = hiT_ws + (size_t)BSZ * CTXT_SZ;        // 528384 B

  prep_kernel<<<257, 256, 0, stream>>>(ctx_in, Wp, mask, maskbits_ws,
                                       hiT_ws, loT_ws);
  attn_main<<<dim3(HW / RPB, BSZ), 256, 0, stream>>>(x, ws, out0, out1);
}